// Round 10
// baseline (235.146 us; speedup 1.0000x reference)
//
#include <hip/hip_runtime.h>
#include <hip/hip_bf16.h>
#include <math.h>

#define NB    8
#define CDIM  512
#define NSP   4096
#define NHEAD 8

typedef short short8 __attribute__((ext_vector_type(8)));
typedef float f32x4  __attribute__((ext_vector_type(4)));

__device__ __forceinline__ unsigned short f2bf(float f) {
    unsigned int u = __float_as_uint(f);
    u += 0x7fff + ((u >> 16) & 1);          // round-to-nearest-even
    return (unsigned short)(u >> 16);
}
__device__ __forceinline__ float bf2f(unsigned short s) {
    return __uint_as_float(((unsigned int)s) << 16);
}
__device__ __forceinline__ void gld_lds16(const void* g, void* s) {
    __builtin_amdgcn_global_load_lds(
        (const __attribute__((address_space(1))) unsigned int*)g,
        (__attribute__((address_space(3))) unsigned int*)s, 16, 0, 0);
}
__device__ __forceinline__ void split8(const float* s, short8& hi, short8& lo) {
    float4 a = *reinterpret_cast<const float4*>(s);
    float4 b = *reinterpret_cast<const float4*>(s + 4);
    float v[8] = {a.x, a.y, a.z, a.w, b.x, b.y, b.z, b.w};
    #pragma unroll
    for (int j = 0; j < 8; ++j) {
        unsigned short hh = f2bf(v[j]);
        hi[j] = (short)hh;
        lo[j] = (short)f2bf(v[j] - bf2f(hh));
    }
}

// ---------------------------------------------------------------------------
// x -> fragment-linear hi/lo bf16 (B-operand layout) via LDS transpose
// ---------------------------------------------------------------------------
__global__ __launch_bounds__(256) void convert_x(const float* __restrict__ x,
    unsigned short* __restrict__ xh, unsigned short* __restrict__ xl)
{
    const int cb4 = blockIdx.x;
    const int kt  = blockIdx.y;
    const int b   = blockIdx.z;
    const int tid = threadIdx.x;

    __shared__ float sx[32][65];

    const int r  = tid >> 3;
    const int c8 = (tid & 7) * 8;
    const float* xp = x + ((long)b * CDIM + kt * 32 + r) * NSP + cb4 * 64 + c8;
    float4 v0 = *reinterpret_cast<const float4*>(xp);
    float4 v1 = *reinterpret_cast<const float4*>(xp + 4);
    sx[r][c8 + 0] = v0.x; sx[r][c8 + 1] = v0.y; sx[r][c8 + 2] = v0.z; sx[r][c8 + 3] = v0.w;
    sx[r][c8 + 4] = v1.x; sx[r][c8 + 5] = v1.y; sx[r][c8 + 6] = v1.z; sx[r][c8 + 7] = v1.w;
    __syncthreads();

    const int cb_l  = tid >> 6;
    const int lane  = tid & 63;
    const int cb    = cb4 * 4 + cb_l;
    const int col_l = cb_l * 16 + (lane & 15);
    const int k0    = (lane >> 4) * 8;
    short8 hv, lv;
    #pragma unroll
    for (int j = 0; j < 8; ++j) {
        float v = sx[k0 + j][col_l];
        unsigned short hh = f2bf(v);
        hv[j] = (short)hh;
        lv[j] = (short)f2bf(v - bf2f(hh));
    }
    const long base = (((long)(b * 256 + cb) * 16 + kt) * 512) + lane * 8;
    *reinterpret_cast<short8*>(xh + base) = hv;
    *reinterpret_cast<short8*>(xl + base) = lv;
}

// ---------------------------------------------------------------------------
// w[R][512] row-major -> A-operand hi/lo frags. grid (R/16, 16), blk 64
// ---------------------------------------------------------------------------
__global__ __launch_bounds__(64) void convert_w(const float* __restrict__ w,
    unsigned short* __restrict__ wh, unsigned short* __restrict__ wl)
{
    const int lane = threadIdx.x & 63;
    const int rb = blockIdx.x;
    const int kt = blockIdx.y;
    const int row = rb * 16 + (lane & 15);
    const int k0  = kt * 32 + (lane >> 4) * 8;
    const float* wp = w + (long)row * CDIM + k0;
    const long base = ((long)rb * 16 + kt) * 512 + lane * 8;
    short8 hv, lv;
    #pragma unroll
    for (int j = 0; j < 8; ++j) {
        float v = wp[j];
        unsigned short h = f2bf(v);
        hv[j] = (short)h;
        lv[j] = (short)f2bf(v - bf2f(h));
    }
    *reinterpret_cast<short8*>(wh + base) = hv;
    *reinterpret_cast<short8*>(wl + base) = lv;
}

// ---------------------------------------------------------------------------
// src[K=512][C] row-major -> B-operand hi/lo frags
// ---------------------------------------------------------------------------
__global__ __launch_bounds__(64) void convert_b(const float* __restrict__ src,
    int ld, unsigned short* __restrict__ bh, unsigned short* __restrict__ bl)
{
    const int lane = threadIdx.x & 63;
    const int cb = blockIdx.x;
    const int kt = blockIdx.y;
    const int col = cb * 16 + (lane & 15);
    const int k0  = kt * 32 + (lane >> 4) * 8;
    const float* sp = src + (long)k0 * ld + col;
    const long base = ((long)cb * 16 + kt) * 512 + lane * 8;
    short8 hv, lv;
    #pragma unroll
    for (int j = 0; j < 8; ++j) {
        float v = sp[(long)j * ld];
        unsigned short h = f2bf(v);
        hv[j] = (short)h;
        lv[j] = (short)f2bf(v - bf2f(h));
    }
    *reinterpret_cast<short8*>(bh + base) = hv;
    *reinterpret_cast<short8*>(bl + base) = lv;
}

// ---------------------------------------------------------------------------
// FUSED, 8-wave: per (n-chunk 256, head, batch) block:
// KV[128][256] = Wkv_h @ x via split-bf16 MFMA (2-barrier loop, 48 KiB LDS,
// 8 waves 2Mx4N so 2 blocks/CU = 4 waves/SIMD), then epilogue:
// exp + row-sum atomics (wr==0 waves), P.V^T via quarter LDS bounce,
// atomic ctx accumulate.
// ---------------------------------------------------------------------------
__global__ __launch_bounds__(512, 4) void fused_kv_ctx(
    const unsigned short* __restrict__ Ah, const unsigned short* __restrict__ Al,
    const unsigned short* __restrict__ Bh, const unsigned short* __restrict__ Bl,
    float* __restrict__ ctx, float* __restrict__ ssum)
{
    const int ch = blockIdx.x;   // 0..15 n-chunk
    const int h  = blockIdx.y;
    const int b  = blockIdx.z;
    const int tid  = threadIdx.x;
    const int lane = tid & 63;
    const int wid  = tid >> 6;   // 0..7
    const int wr = wid >> 2;     // 0: K rows, 1: V rows
    const int wc = wid & 3;      // col quarter 0..3

    __shared__ __align__(16) char lds[49152];

    f32x4 acc[4][4];
    #pragma unroll
    for (int m = 0; m < 4; ++m)
        #pragma unroll
        for (int n = 0; n < 4; ++n)
            acc[m][n] = (f32x4){0.f, 0.f, 0.f, 0.f};

    // 48 staging blocks: 0-7 Ahi(sub), 8-15 Alo, 16-31 Bhi(j), 32-47 Blo(j)
    const unsigned short* srcs[6];
    #pragma unroll
    for (int i = 0; i < 6; ++i) {
        const int blk = wid * 6 + i;
        const unsigned short* s;
        if (blk < 16) {
            const int sub = blk & 7;
            const int rb = (sub < 4) ? (h * 4 + sub) : (32 + h * 4 + (sub - 4));
            s = ((blk < 8) ? Ah : Al) + ((long)(rb * 16) << 9);
        } else {
            const int j = (blk - 16) & 15;
            const int cb = ch * 16 + j;
            s = ((blk < 32) ? Bh : Bl) + (((long)(b * 256 + cb) * 16) << 9);
        }
        srcs[i] = s + lane * 8;
    }

    for (int kt = 0; kt < 16; ++kt) {
        #pragma unroll
        for (int i = 0; i < 6; ++i) {
            gld_lds16(srcs[i], lds + (wid * 6 + i) * 1024);
            srcs[i] += 512;
        }
        __syncthreads();

        short8 ah[4], al[4];
        #pragma unroll
        for (int m = 0; m < 4; ++m) {
            ah[m] = *reinterpret_cast<const short8*>(lds +        (wr * 4 + m) * 1024 + lane * 16);
            al[m] = *reinterpret_cast<const short8*>(lds + 8192 + (wr * 4 + m) * 1024 + lane * 16);
        }
        #pragma unroll
        for (int n = 0; n < 4; ++n) {
            short8 bh = *reinterpret_cast<const short8*>(lds + 16384 + (wc * 4 + n) * 1024 + lane * 16);
            short8 bl = *reinterpret_cast<const short8*>(lds + 32768 + (wc * 4 + n) * 1024 + lane * 16);
            #pragma unroll
            for (int m = 0; m < 4; ++m) {
                acc[m][n] = __builtin_amdgcn_mfma_f32_16x16x32_bf16(ah[m], bh, acc[m][n], 0, 0, 0);
                acc[m][n] = __builtin_amdgcn_mfma_f32_16x16x32_bf16(ah[m], bl, acc[m][n], 0, 0, 0);
                acc[m][n] = __builtin_amdgcn_mfma_f32_16x16x32_bf16(al[m], bh, acc[m][n], 0, 0, 0);
            }
        }
        __syncthreads();
    }

    // ---- epilogue: exp on K rows (wr==0) + row-sum atomics (per quarter) ----
    if (wr == 0) {
        #pragma unroll
        for (int m = 0; m < 4; ++m)
            #pragma unroll
            for (int j = 0; j < 4; ++j) {
                float s = 0.f;
                #pragma unroll
                for (int n = 0; n < 4; ++n) {
                    float e = __expf(acc[m][n][j]);
                    acc[m][n][j] = e;
                    s += e;
                }
                s += __shfl_xor(s, 1); s += __shfl_xor(s, 2);
                s += __shfl_xor(s, 4); s += __shfl_xor(s, 8);
                if ((lane & 15) == 0)
                    atomicAdd(&ssum[b * 512 + h * 64 + m * 16 + (lane >> 4) * 4 + j], s);
            }
    }

    // ---- ctx = P . V^T over this 256-col chunk, 4 quarters of k=64 ----
    float* Plds = (float*)lds;                       // [64][68] fp32
    float* Vlds = (float*)(lds + 64 * 68 * 4);       // [64][68] fp32
    f32x4 acc2[2];
    acc2[0] = (f32x4){0.f, 0.f, 0.f, 0.f};
    acc2[1] = (f32x4){0.f, 0.f, 0.f, 0.f};

    #pragma unroll
    for (int q = 0; q < 4; ++q) {
        __syncthreads();
        if (wc == q) {                     // wave (0,q) writes P, (1,q) writes V
            float* T = (wr == 0) ? Plds : Vlds;
            #pragma unroll
            for (int m = 0; m < 4; ++m)
                #pragma unroll
                for (int n = 0; n < 4; ++n)
                    #pragma unroll
                    for (int j = 0; j < 4; ++j)
                        T[(m * 16 + (lane >> 4) * 4 + j) * 68 + n * 16 + (lane & 15)]
                            = acc[m][n][j];
        }
        __syncthreads();

        #pragma unroll
        for (int ks = 0; ks < 2; ++ks) {
            const int kcol = ks * 32 + (lane >> 4) * 8;
            short8 pa_h[2], pa_l[2], vb_h, vb_l;
            #pragma unroll
            for (int mi = 0; mi < 2; ++mi)
                split8(&Plds[(wr * 32 + mi * 16 + (lane & 15)) * 68 + kcol], pa_h[mi], pa_l[mi]);
            split8(&Vlds[(wc * 16 + (lane & 15)) * 68 + kcol], vb_h, vb_l);
            #pragma unroll
            for (int mi = 0; mi < 2; ++mi) {
                acc2[mi] = __builtin_amdgcn_mfma_f32_16x16x32_bf16(pa_h[mi], vb_h, acc2[mi], 0, 0, 0);
                acc2[mi] = __builtin_amdgcn_mfma_f32_16x16x32_bf16(pa_h[mi], vb_l, acc2[mi], 0, 0, 0);
                acc2[mi] = __builtin_amdgcn_mfma_f32_16x16x32_bf16(pa_l[mi], vb_h, acc2[mi], 0, 0, 0);
            }
        }
    }

    float* cp = ctx + (long)(b * NHEAD + h) * 4096;
    #pragma unroll
    for (int mi = 0; mi < 2; ++mi) {
        const int d0 = wr * 32 + mi * 16;
        const int e  = wc * 16 + (lane & 15);
        #pragma unroll
        for (int j = 0; j < 4; ++j)
            atomicAdd(&cp[(d0 + (lane >> 4) * 4 + j) * 64 + e], acc2[mi][j]);
    }
}

// ---------------------------------------------------------------------------
// 256x256-tile split-bf16 MFMA GEMM, 2-phase counted-vmcnt(8) (proven).
// ---------------------------------------------------------------------------
template<int NKT, bool BIAS>
__global__ __launch_bounds__(512, 2) void gemm_mfma256(
    const unsigned short* __restrict__ Ah, const unsigned short* __restrict__ Al,
    const unsigned short* __restrict__ Bh, const unsigned short* __restrict__ Bl,
    float* __restrict__ C, const float* __restrict__ bias,
    int N, int aBatchRB, int bBatchCB, long cBatch)
{
    const int b    = blockIdx.z;
    const int tid  = threadIdx.x;
    const int lane = tid & 63;
    const int wid  = tid >> 6;        // 0..7
    const int wr   = wid >> 2;        // 0..1 (M)
    const int wc   = wid & 3;         // 0..3 (N)

    __shared__ __align__(16) char lds[2][65536];

    f32x4 acc[8][4];
    #pragma unroll
    for (int m = 0; m < 8; ++m)
        #pragma unroll
        for (int n = 0; n < 4; ++n)
            acc[m][n] = (f32x4){0.f, 0.f, 0.f, 0.f};

    const int rb0 = b * aBatchRB + blockIdx.y * 16;
    const int cb0 = b * bBatchCB + blockIdx.x * 16;

    const unsigned short* srcs[8];
    #pragma unroll
    for (int i = 0; i < 8; ++i) {
        const int blk = wid * 8 + i;
        const int sub = blk & 15;
        const unsigned short* s;
        if (blk < 16)      s = Ah + ((long)(rb0 + sub) * NKT << 9);
        else if (blk < 32) s = Al + ((long)(rb0 + sub) * NKT << 9);
        else if (blk < 48) s = Bh + ((long)(cb0 + sub) * NKT << 9);
        else               s = Bl + ((long)(cb0 + sub) * NKT << 9);
        srcs[i] = s + lane * 8;
    }
    const int ldsoff = wid * 8192;

    #pragma unroll
    for (int i = 0; i < 8; ++i) {
        gld_lds16(srcs[i], &lds[0][ldsoff + i * 1024]);
        srcs[i] += 512;
    }

    int cur = 0;
    for (int kt = 0; kt < NKT; ++kt) {
        if (kt + 1 < NKT) {
            #pragma unroll
            for (int i = 0; i < 8; ++i) {
                gld_lds16(srcs[i], &lds[cur ^ 1][ldsoff + i * 1024]);
                srcs[i] += 512;
            }
            asm volatile("s_waitcnt vmcnt(8)" ::: "memory");
        } else {
            asm volatile("s_waitcnt vmcnt(0)" ::: "memory");
        }
        __builtin_amdgcn_s_barrier();

        const char* L = lds[cur];
        short8 ah[8], al[8];
        #pragma unroll
        for (int m = 0; m < 8; ++m) {
            ah[m] = *reinterpret_cast<const short8*>(L +         (wr * 8 + m) * 1024 + lane * 16);
            al[m] = *reinterpret_cast<const short8*>(L + 16384 + (wr * 8 + m) * 1024 + lane * 16);
        }
        __builtin_amdgcn_s_setprio(1);
        #pragma unroll
        for (int n = 0; n < 4; ++n) {
            short8 bh = *reinterpret_cast<const short8*>(L + 32768 + (wc * 4 + n) * 1024 + lane * 16);
            short8 bl = *reinterpret_cast<const short8*>(L + 49152 + (wc * 4 + n) * 1024 + lane * 16);
            #pragma unroll
            for (int m = 0; m < 8; ++m) {
                acc[m][n] = __builtin_amdgcn_mfma_f32_16x16x32_bf16(ah[m], bh, acc[m][n], 0, 0, 0);
                acc[m][n] = __builtin_amdgcn_mfma_f32_16x16x32_bf16(ah[m], bl, acc[m][n], 0, 0, 0);
                acc[m][n] = __builtin_amdgcn_mfma_f32_16x16x32_bf16(al[m], bh, acc[m][n], 0, 0, 0);
            }
        }
        __builtin_amdgcn_s_setprio(0);
        asm volatile("" ::: "memory");
        __builtin_amdgcn_s_barrier();
        asm volatile("" ::: "memory");
        cur ^= 1;
    }

    const int row0 = blockIdx.y * 256 + wr * 128;
    const int col0 = blockIdx.x * 256 + wc * 64;
    float* Cb = C + (long)b * cBatch;
    #pragma unroll
    for (int m = 0; m < 8; ++m)
        #pragma unroll
        for (int n = 0; n < 4; ++n) {
            const int col = col0 + n * 16 + (lane & 15);
            #pragma unroll
            for (int j = 0; j < 4; ++j) {
                const int row = row0 + m * 16 + (lane >> 4) * 4 + j;
                float v = acc[m][n][j];
                if (BIAS) v += bias[row];
                Cb[(long)row * N + col] = v;
            }
        }
}

__global__ __launch_bounds__(256) void zero_buf(float* p, int n) {
    for (int i = blockIdx.x * 256 + threadIdx.x; i < n; i += gridDim.x * 256) p[i] = 0.f;
}

// ---------------------------------------------------------------------------
// gemm_w3: 128x128 split-bf16 MFMA GEMM computing W3 = Amat @ Wq, emitting
// A-operand hi/lo frags DIRECTLY (LDS bounce) -- no fp32 W3, no convert pass.
// grid (4, 4, NB), 256 thr.
// ---------------------------------------------------------------------------
__global__ __launch_bounds__(256) void gemm_w3(
    const unsigned short* __restrict__ Ah, const unsigned short* __restrict__ Al,
    const unsigned short* __restrict__ Bh, const unsigned short* __restrict__ Bl,
    unsigned short* __restrict__ w3h, unsigned short* __restrict__ w3l)
{
    const int b    = blockIdx.z;
    const int tid  = threadIdx.x;
    const int lane = tid & 63;
    const int wid  = tid >> 6;
    const int wr   = wid >> 1;
    const int wc   = wid & 1;

    __shared__ __align__(16) char lds[64 * 132 * 4];   // staging uses first 32KB

    f32x4 acc[4][4];
    #pragma unroll
    for (int m = 0; m < 4; ++m)
        #pragma unroll
        for (int n = 0; n < 4; ++n) acc[m][n] = (f32x4){0.f, 0.f, 0.f, 0.f};

    const int rb0 = b * 32 + blockIdx.y * 8;
    const int cb0 = blockIdx.x * 8;

    const unsigned short* srcs[8];
    #pragma unroll
    for (int i = 0; i < 8; ++i) {
        const int blk = wid * 8 + i;
        const int sub = blk & 7;
        const unsigned short* s;
        if (blk < 8)       s = Ah + ((long)(rb0 + sub) * 16 << 9);
        else if (blk < 16) s = Al + ((long)(rb0 + sub) * 16 << 9);
        else if (blk < 24) s = Bh + ((long)(cb0 + sub) * 16 << 9);
        else               s = Bl + ((long)(cb0 + sub) * 16 << 9);
        srcs[i] = s + lane * 8;
    }

    for (int kt = 0; kt < 16; ++kt) {
        #pragma unroll
        for (int i = 0; i < 8; ++i) {
            gld_lds16(srcs[i], lds + (wid * 8 + i) * 1024);
            srcs[i] += 512;
        }
        __syncthreads();

        short8 ah[4], al[4], bh[4], bl[4];
        #pragma unroll
        for (int m = 0; m < 4; ++m) {
            ah[m] = *reinterpret_cast<const short8*>(lds +         (wr * 4 + m) * 1024 + lane * 16);
            al[m] = *reinterpret_cast<const short8*>(lds +  8192 + (wr * 4 + m) * 1024 + lane * 16);
        }
        #pragma unroll
        for (int n = 0; n < 4; ++n) {
            bh[n] = *reinterpret_cast<const short8*>(lds + 16384 + (wc * 4 + n) * 1024 + lane * 16);
            bl[n] = *reinterpret_cast<const short8*>(lds + 24576 + (wc * 4 + n) * 1024 + lane * 16);
        }
        #pragma unroll
        for (int m = 0; m < 4; ++m)
            #pragma unroll
            for (int n = 0; n < 4; ++n) {
                acc[m][n] = __builtin_amdgcn_mfma_f32_16x16x32_bf16(ah[m], bh[n], acc[m][n], 0, 0, 0);
                acc[m][n] = __builtin_amdgcn_mfma_f32_16x16x32_bf16(ah[m], bl[n], acc[m][n], 0, 0, 0);
                acc[m][n] = __builtin_amdgcn_mfma_f32_16x16x32_bf16(al[m], bh[n], acc[m][n], 0, 0, 0);
            }
        __syncthreads();
    }

    // epilogue: bounce C in 64-row halves -> emit frags
    float* Ct = (float*)lds;   // [64][132]
    #pragma unroll
    for (int hf = 0; hf < 2; ++hf) {
        __syncthreads();
        if (wr == hf) {
            #pragma unroll
            for (int m = 0; m < 4; ++m)
                #pragma unroll
                for (int n = 0; n < 4; ++n)
                    #pragma unroll
                    for (int j = 0; j < 4; ++j)
                        Ct[(m * 16 + (lane >> 4) * 4 + j) * 132 + wc * 64 + n * 16 + (lane & 15)]
                            = acc[m][n][j];
        }
        __syncthreads();
        #pragma unroll
        for (int i = 0; i < 4; ++i) {
            const int blkid = wid * 4 + i;       // 0..15
            const int rbl = blkid >> 2, ktl = blkid & 3;
            short8 hv, lv;
            #pragma unroll
            for (int jj = 0; jj < 8; ++jj) {
                float v = Ct[(rbl * 16 + (lane & 15)) * 132 + ktl * 32 + (lane >> 4) * 8 + jj];
                unsigned short hh = f2bf(v);
                hv[jj] = (short)hh;
                lv[jj] = (short)f2bf(v - bf2f(hh));
            }
            const int rbG = b * 32 + blockIdx.y * 8 + hf * 4 + rbl;
            const int ktG = blockIdx.x * 4 + ktl;
            const long base = ((long)rbG * 16 + ktG) * 512 + lane * 8;
            *reinterpret_cast<short8*>(w3h + base) = hv;
            *reinterpret_cast<short8*>(w3l + base) = lv;
        }
    }
}

// ---------------------------------------------------------------------------
// ctx_fold2: Amat tile folded with normalized ctx, emitted directly as
// A-operand hi/lo frags.  grid (8 o-slices, NHEAD, NB), 256 thr.
// ---------------------------------------------------------------------------
__global__ __launch_bounds__(256) void ctx_fold2(
    const float* __restrict__ w_out, const float* __restrict__ ctx,
    const float* __restrict__ ssum,
    unsigned short* __restrict__ amh, unsigned short* __restrict__ aml)
{
    const int o0 = blockIdx.x * 64;
    const int h  = blockIdx.y;
    const int b  = blockIdx.z;
    const int tid = threadIdx.x;

    __shared__ float Wo[64][65];
    __shared__ float Ct[64][65];
    __shared__ float At[64][65];

    for (int idx = tid; idx < 64 * 16; idx += 256) {
        const int r = idx >> 4;
        const int c = (idx & 15) * 4;
        float4 w4 = *reinterpret_cast<const float4*>(&w_out[(long)(o0 + r) * CDIM + h * 64 + c]);
        Wo[r][c + 0] = w4.x; Wo[r][c + 1] = w4.y; Wo[r][c + 2] = w4.z; Wo[r][c + 3] = w4.w;
        float4 c4 = *reinterpret_cast<const float4*>(&ctx[(((long)(b * NHEAD + h) * 64 + r) * 64) + c]);
        Ct[r][c + 0] = c4.x; Ct[r][c + 1] = c4.y; Ct[r][c + 2] = c4.z; Ct[r][c + 3] = c4.w;
    }
    __syncthreads();

    const int to = tid >> 4, td = tid & 15;
    float acc[4][4];
    #pragma unroll
    for (int i = 0; i < 4; ++i)
        #pragma unroll
        for (int j = 0; j < 4; ++j) acc[i][j] = 0.f;

    for (int e = 0; e < 64; ++e) {
        float ro[4], rd[4];
        #pragma unroll
        for (int i = 0; i < 4; ++i) ro[i] = Wo[to * 4 + i][e];
        #pragma unroll
        for (int j = 0; j < 4; ++j) rd[j] = Ct[td * 4 + j][e];
        #pragma unroll
        for (int i = 0; i < 4; ++i)
            #pragma unroll
            for (int j = 0; j < 4; ++j) acc[i][j] += ro[i] * rd[j];
    }

    #pragma unroll
    for (int j = 0; j < 4; ++j) {
        const float s = 1.f / ssum[b * 512 + h * 64 + td * 4 + j];
        #pragma unroll
        for (int i = 0; i < 4; ++i)
            At[to * 4 + i][td * 4 + j] = acc[i][j] * s;
    }
    __syncthreads();

    const int g = tid >> 6, lane = tid & 63;
    #pragma unroll
    for (int kt_l = 0; kt_l < 2; ++kt_l) {
        short8 hv, lv;
        #pragma unroll
        for (int jj = 0; jj < 8; ++jj) {
            float v = At[g * 16 + (lane & 15)][kt_l * 32 + (lane >> 4) * 8 + jj];
            unsigned short hh = f2bf(v);
            hv[jj] = (short)hh;
            lv[jj] = (short)f2bf(v - bf2f(hh));
        }
        const long base = (((long)(b * 32 + (o0 >> 4) + g) * 16) + (h * 2 + kt_l)) * 512 + lane * 8;
        *reinterpret_cast<short8*>(amh + base) = hv;
        *reinterpret_cast<short8*>(aml + base) = lv;
    }
}

// ---------------------------------------------------------------------------
extern "C" void kernel_launch(void* const* d_in, const int* in_sizes, int n_in,
                              void* d_out, int out_size, void* d_ws, size_t ws_size,
                              hipStream_t stream) {
    (void)in_sizes; (void)n_in; (void)out_size; (void)ws_size;
    const float* x     = (const float*)d_in[0];
    const float* w_qkv = (const float*)d_in[1];
    const float* w_out = (const float*)d_in[2];
    const float* b_out = (const float*)d_in[3];
    float* out = (float*)d_out;

    char* ws = (char*)d_ws;
    unsigned short* xh   = (unsigned short*)(ws + 134217728L);        // 32 MiB
    unsigned short* xl   = (unsigned short*)(ws + 167772160L);        // 32 MiB
    unsigned short* wkvh = (unsigned short*)(ws + 201326592L);        // 1 MiB
    unsigned short* wkvl = (unsigned short*)(ws + 202375168L);        // 1 MiB
    float*          ssum = (float*)(ws + 203423744L);                 // 16 KiB
    float*          ctx  = (float*)(ws + 203440128L);                 // 1 MiB
    unsigned short* amh  = (unsigned short*)(ws + 16777216L);         // 4 MiB
    unsigned short* aml  = (unsigned short*)(ws + 20971520L);         // 4 MiB
    unsigned short* wqh  = (unsigned short*)(ws + 25165824L);         // 1 MiB
    unsigned short* wql  = (unsigned short*)(ws + 26214400L);         // 1 MiB
    unsigned short* w3h  = (unsigned short*)(ws + 27262976L);         // 4 MiB
    unsigned short* w3l  = (unsigned short*)(ws + 31457280L);         // 4 MiB

    // 1) conversions + zero accumulators
    convert_x<<<dim3(64, 16, NB), 256, 0, stream>>>(x, xh, xl);
    convert_w<<<dim3(64, 16), 64, 0, stream>>>(w_qkv + 512L * CDIM, wkvh, wkvl);
    zero_buf<<<256, 256, 0, stream>>>(ssum, (16384 + 1048576) / 4);

    // 2) FUSED 8-wave: KV GEMM + exp + row sums + ctx accumulation
    fused_kv_ctx<<<dim3(16, NHEAD, NB), 512, 0, stream>>>(
        wkvh, wkvl, xh, xl, ctx, ssum);

    // 3) Wq -> B-frags
    convert_b<<<dim3(32, 16), 64, 0, stream>>>(w_qkv, CDIM, wqh, wql);

    // 4) fold ctx into W_out -> Amat frags directly
    ctx_fold2<<<dim3(8, NHEAD, NB), 256, 0, stream>>>(w_out, ctx, ssum, amh, aml);

    // 5) W3 = Amat @ Wq via MFMA, emitting W3 frags directly
    gemm_w3<<<dim3(4, 4, NB), 256, 0, stream>>>(amh, aml, wqh, wql, w3h, w3l);

    // 6) out = W3 @ x + b_out  (2-phase 256^2, proven)
    gemm_mfma256<16, true><<<dim3(16, 2, NB), 512, 0, stream>>>(
        w3h, w3l, xh, xl, out, b_out, NSP, 32, 256, (long)CDIM * NSP);
}

// Round 11
// 215.381 us; speedup vs baseline: 1.0918x; 1.0918x over previous
//
#include <hip/hip_runtime.h>
#include <hip/hip_bf16.h>
#include <math.h>

#define NB    8
#define CDIM  512
#define NSP   4096
#define NHEAD 8

typedef short short8 __attribute__((ext_vector_type(8)));
typedef float f32x4  __attribute__((ext_vector_type(4)));

__device__ __forceinline__ unsigned short f2bf(float f) {
    unsigned int u = __float_as_uint(f);
    u += 0x7fff + ((u >> 16) & 1);          // round-to-nearest-even
    return (unsigned short)(u >> 16);
}
__device__ __forceinline__ float bf2f(unsigned short s) {
    return __uint_as_float(((unsigned int)s) << 16);
}
__device__ __forceinline__ void gld_lds16(const void* g, void* s) {
    __builtin_amdgcn_global_load_lds(
        (const __attribute__((address_space(1))) unsigned int*)g,
        (__attribute__((address_space(3))) unsigned int*)s, 16, 0, 0);
}
__device__ __forceinline__ void split8(const float* s, short8& hi, short8& lo) {
    float4 a = *reinterpret_cast<const float4*>(s);
    float4 b = *reinterpret_cast<const float4*>(s + 4);
    float v[8] = {a.x, a.y, a.z, a.w, b.x, b.y, b.z, b.w};
    #pragma unroll
    for (int j = 0; j < 8; ++j) {
        unsigned short hh = f2bf(v[j]);
        hi[j] = (short)hh;
        lo[j] = (short)f2bf(v[j] - bf2f(hh));
    }
}

// ---------------------------------------------------------------------------
// x -> fragment-linear hi/lo bf16 (B-operand layout) via LDS transpose
// ---------------------------------------------------------------------------
__global__ __launch_bounds__(256) void convert_x(const float* __restrict__ x,
    unsigned short* __restrict__ xh, unsigned short* __restrict__ xl)
{
    const int cb4 = blockIdx.x;
    const int kt  = blockIdx.y;
    const int b   = blockIdx.z;
    const int tid = threadIdx.x;

    __shared__ float sx[32][65];

    const int r  = tid >> 3;
    const int c8 = (tid & 7) * 8;
    const float* xp = x + ((long)b * CDIM + kt * 32 + r) * NSP + cb4 * 64 + c8;
    float4 v0 = *reinterpret_cast<const float4*>(xp);
    float4 v1 = *reinterpret_cast<const float4*>(xp + 4);
    sx[r][c8 + 0] = v0.x; sx[r][c8 + 1] = v0.y; sx[r][c8 + 2] = v0.z; sx[r][c8 + 3] = v0.w;
    sx[r][c8 + 4] = v1.x; sx[r][c8 + 5] = v1.y; sx[r][c8 + 6] = v1.z; sx[r][c8 + 7] = v1.w;
    __syncthreads();

    const int cb_l  = tid >> 6;
    const int lane  = tid & 63;
    const int cb    = cb4 * 4 + cb_l;
    const int col_l = cb_l * 16 + (lane & 15);
    const int k0    = (lane >> 4) * 8;
    short8 hv, lv;
    #pragma unroll
    for (int j = 0; j < 8; ++j) {
        float v = sx[k0 + j][col_l];
        unsigned short hh = f2bf(v);
        hv[j] = (short)hh;
        lv[j] = (short)f2bf(v - bf2f(hh));
    }
    const long base = (((long)(b * 256 + cb) * 16 + kt) * 512) + lane * 8;
    *reinterpret_cast<short8*>(xh + base) = hv;
    *reinterpret_cast<short8*>(xl + base) = lv;
}

// ---------------------------------------------------------------------------
// w[R][512] row-major -> A-operand hi/lo frags. grid (R/16, 16), blk 64
// ---------------------------------------------------------------------------
__global__ __launch_bounds__(64) void convert_w(const float* __restrict__ w,
    unsigned short* __restrict__ wh, unsigned short* __restrict__ wl)
{
    const int lane = threadIdx.x & 63;
    const int rb = blockIdx.x;
    const int kt = blockIdx.y;
    const int row = rb * 16 + (lane & 15);
    const int k0  = kt * 32 + (lane >> 4) * 8;
    const float* wp = w + (long)row * CDIM + k0;
    const long base = ((long)rb * 16 + kt) * 512 + lane * 8;
    short8 hv, lv;
    #pragma unroll
    for (int j = 0; j < 8; ++j) {
        float v = wp[j];
        unsigned short h = f2bf(v);
        hv[j] = (short)h;
        lv[j] = (short)f2bf(v - bf2f(h));
    }
    *reinterpret_cast<short8*>(wh + base) = hv;
    *reinterpret_cast<short8*>(wl + base) = lv;
}

// ---------------------------------------------------------------------------
// src[K=512][C] row-major -> B-operand hi/lo frags
// ---------------------------------------------------------------------------
__global__ __launch_bounds__(64) void convert_b(const float* __restrict__ src,
    int ld, unsigned short* __restrict__ bh, unsigned short* __restrict__ bl)
{
    const int lane = threadIdx.x & 63;
    const int cb = blockIdx.x;
    const int kt = blockIdx.y;
    const int col = cb * 16 + (lane & 15);
    const int k0  = kt * 32 + (lane >> 4) * 8;
    const float* sp = src + (long)k0 * ld + col;
    const long base = ((long)cb * 16 + kt) * 512 + lane * 8;
    short8 hv, lv;
    #pragma unroll
    for (int j = 0; j < 8; ++j) {
        float v = sp[(long)j * ld];
        unsigned short h = f2bf(v);
        hv[j] = (short)h;
        lv[j] = (short)f2bf(v - bf2f(h));
    }
    *reinterpret_cast<short8*>(bh + base) = hv;
    *reinterpret_cast<short8*>(bl + base) = lv;
}

// ---------------------------------------------------------------------------
// FUSED (round-7/9 proven, 4 waves): per (n-chunk 256, head, batch) block:
// KV[128][256] = Wkv_h @ x via split-bf16 MFMA (2-barrier loop, 48 KiB LDS),
// then exp + row-sum atomics + P.V^T via LDS bounce, atomic ctx accumulate.
// ---------------------------------------------------------------------------
__global__ __launch_bounds__(256, 2) void fused_kv_ctx(
    const unsigned short* __restrict__ Ah, const unsigned short* __restrict__ Al,
    const unsigned short* __restrict__ Bh, const unsigned short* __restrict__ Bl,
    float* __restrict__ ctx, float* __restrict__ ssum)
{
    const int ch = blockIdx.x;   // 0..15 n-chunk
    const int h  = blockIdx.y;
    const int b  = blockIdx.z;
    const int tid  = threadIdx.x;
    const int lane = tid & 63;
    const int wid  = tid >> 6;
    const int wr = wid >> 1, wc = wid & 1;

    __shared__ __align__(16) char lds[49152];

    f32x4 acc[4][8];
    #pragma unroll
    for (int m = 0; m < 4; ++m)
        #pragma unroll
        for (int n = 0; n < 8; ++n)
            acc[m][n] = (f32x4){0.f, 0.f, 0.f, 0.f};

    // 48 staging blocks: 0-7 Ahi(sub), 8-15 Alo, 16-31 Bhi(j), 32-47 Blo(j)
    const unsigned short* srcs[12];
    #pragma unroll
    for (int i = 0; i < 12; ++i) {
        const int blk = wid * 12 + i;
        const unsigned short* s;
        if (blk < 16) {
            const int sub = blk & 7;
            const int rb = (sub < 4) ? (h * 4 + sub) : (32 + h * 4 + (sub - 4));
            s = ((blk < 8) ? Ah : Al) + ((long)(rb * 16) << 9);
        } else {
            const int j = (blk - 16) & 15;
            const int cb = ch * 16 + j;
            s = ((blk < 32) ? Bh : Bl) + (((long)(b * 256 + cb) * 16) << 9);
        }
        srcs[i] = s + lane * 8;
    }

    for (int kt = 0; kt < 16; ++kt) {
        #pragma unroll
        for (int i = 0; i < 12; ++i) {
            gld_lds16(srcs[i], lds + (wid * 12 + i) * 1024);
            srcs[i] += 512;
        }
        __syncthreads();

        short8 ah[4], al[4];
        #pragma unroll
        for (int m = 0; m < 4; ++m) {
            ah[m] = *reinterpret_cast<const short8*>(lds +        (wr * 4 + m) * 1024 + lane * 16);
            al[m] = *reinterpret_cast<const short8*>(lds + 8192 + (wr * 4 + m) * 1024 + lane * 16);
        }
        #pragma unroll
        for (int n = 0; n < 8; ++n) {
            short8 bh = *reinterpret_cast<const short8*>(lds + 16384 + (wc * 8 + n) * 1024 + lane * 16);
            short8 bl = *reinterpret_cast<const short8*>(lds + 32768 + (wc * 8 + n) * 1024 + lane * 16);
            #pragma unroll
            for (int m = 0; m < 4; ++m) {
                acc[m][n] = __builtin_amdgcn_mfma_f32_16x16x32_bf16(ah[m], bh, acc[m][n], 0, 0, 0);
                acc[m][n] = __builtin_amdgcn_mfma_f32_16x16x32_bf16(ah[m], bl, acc[m][n], 0, 0, 0);
                acc[m][n] = __builtin_amdgcn_mfma_f32_16x16x32_bf16(al[m], bh, acc[m][n], 0, 0, 0);
            }
        }
        __syncthreads();
    }

    // ---- epilogue: exp on K-half (wr==0 waves) + row-sum atomics ----
    if (wr == 0) {
        #pragma unroll
        for (int m = 0; m < 4; ++m)
            #pragma unroll
            for (int j = 0; j < 4; ++j) {
                float s = 0.f;
                #pragma unroll
                for (int n = 0; n < 8; ++n) {
                    float e = __expf(acc[m][n][j]);
                    acc[m][n][j] = e;
                    s += e;
                }
                s += __shfl_xor(s, 1); s += __shfl_xor(s, 2);
                s += __shfl_xor(s, 4); s += __shfl_xor(s, 8);
                if ((lane & 15) == 0)
                    atomicAdd(&ssum[b * 512 + h * 64 + m * 16 + (lane >> 4) * 4 + j], s);
            }
    }

    // ---- ctx = P . V^T over this 256-col chunk, 4 quarters of k=64 ----
    float* Plds = (float*)lds;                       // [64][68] fp32
    float* Vlds = (float*)(lds + 64 * 68 * 4);       // [64][68] fp32
    f32x4 acc2[2][2];
    #pragma unroll
    for (int mi = 0; mi < 2; ++mi)
        #pragma unroll
        for (int ni = 0; ni < 2; ++ni) acc2[mi][ni] = (f32x4){0.f, 0.f, 0.f, 0.f};

    #pragma unroll
    for (int q = 0; q < 4; ++q) {
        __syncthreads();
        if (wc == (q >> 1)) {
            float* T = (wr == 0) ? Plds : Vlds;
            #pragma unroll
            for (int m = 0; m < 4; ++m)
                #pragma unroll
                for (int nn = 0; nn < 4; ++nn)
                    #pragma unroll
                    for (int j = 0; j < 4; ++j)
                        T[(m * 16 + (lane >> 4) * 4 + j) * 68 + nn * 16 + (lane & 15)]
                            = acc[m][(q & 1) * 4 + nn][j];
        }
        __syncthreads();

        #pragma unroll
        for (int ks = 0; ks < 2; ++ks) {
            const int kcol = ks * 32 + (lane >> 4) * 8;
            short8 pa_h[2], pa_l[2], vb_h[2], vb_l[2];
            #pragma unroll
            for (int mi = 0; mi < 2; ++mi)
                split8(&Plds[((wr * 2 + mi) * 16 + (lane & 15)) * 68 + kcol], pa_h[mi], pa_l[mi]);
            #pragma unroll
            for (int ni = 0; ni < 2; ++ni)
                split8(&Vlds[((wc * 2 + ni) * 16 + (lane & 15)) * 68 + kcol], vb_h[ni], vb_l[ni]);
            #pragma unroll
            for (int mi = 0; mi < 2; ++mi)
                #pragma unroll
                for (int ni = 0; ni < 2; ++ni) {
                    acc2[mi][ni] = __builtin_amdgcn_mfma_f32_16x16x32_bf16(pa_h[mi], vb_h[ni], acc2[mi][ni], 0, 0, 0);
                    acc2[mi][ni] = __builtin_amdgcn_mfma_f32_16x16x32_bf16(pa_h[mi], vb_l[ni], acc2[mi][ni], 0, 0, 0);
                    acc2[mi][ni] = __builtin_amdgcn_mfma_f32_16x16x32_bf16(pa_l[mi], vb_h[ni], acc2[mi][ni], 0, 0, 0);
                }
        }
    }

    float* cp = ctx + (long)(b * NHEAD + h) * 4096;
    #pragma unroll
    for (int mi = 0; mi < 2; ++mi)
        #pragma unroll
        for (int ni = 0; ni < 2; ++ni) {
            const int d0 = (wr * 2 + mi) * 16;
            const int e0 = (wc * 2 + ni) * 16;
            #pragma unroll
            for (int j = 0; j < 4; ++j)
                atomicAdd(&cp[(d0 + (lane >> 4) * 4 + j) * 64 + e0 + (lane & 15)], acc2[mi][ni][j]);
        }
}

// ---------------------------------------------------------------------------
// 256x256-tile split-bf16 MFMA GEMM, 2-phase counted-vmcnt(8) (proven).
// ---------------------------------------------------------------------------
template<int NKT, bool BIAS>
__global__ __launch_bounds__(512, 2) void gemm_mfma256(
    const unsigned short* __restrict__ Ah, const unsigned short* __restrict__ Al,
    const unsigned short* __restrict__ Bh, const unsigned short* __restrict__ Bl,
    float* __restrict__ C, const float* __restrict__ bias,
    int N, int aBatchRB, int bBatchCB, long cBatch)
{
    const int b    = blockIdx.z;
    const int tid  = threadIdx.x;
    const int lane = tid & 63;
    const int wid  = tid >> 6;        // 0..7
    const int wr   = wid >> 2;        // 0..1 (M)
    const int wc   = wid & 3;         // 0..3 (N)

    __shared__ __align__(16) char lds[2][65536];

    f32x4 acc[8][4];
    #pragma unroll
    for (int m = 0; m < 8; ++m)
        #pragma unroll
        for (int n = 0; n < 4; ++n)
            acc[m][n] = (f32x4){0.f, 0.f, 0.f, 0.f};

    const int rb0 = b * aBatchRB + blockIdx.y * 16;
    const int cb0 = b * bBatchCB + blockIdx.x * 16;

    const unsigned short* srcs[8];
    #pragma unroll
    for (int i = 0; i < 8; ++i) {
        const int blk = wid * 8 + i;
        const int sub = blk & 15;
        const unsigned short* s;
        if (blk < 16)      s = Ah + ((long)(rb0 + sub) * NKT << 9);
        else if (blk < 32) s = Al + ((long)(rb0 + sub) * NKT << 9);
        else if (blk < 48) s = Bh + ((long)(cb0 + sub) * NKT << 9);
        else               s = Bl + ((long)(cb0 + sub) * NKT << 9);
        srcs[i] = s + lane * 8;
    }
    const int ldsoff = wid * 8192;

    #pragma unroll
    for (int i = 0; i < 8; ++i) {
        gld_lds16(srcs[i], &lds[0][ldsoff + i * 1024]);
        srcs[i] += 512;
    }

    int cur = 0;
    for (int kt = 0; kt < NKT; ++kt) {
        if (kt + 1 < NKT) {
            #pragma unroll
            for (int i = 0; i < 8; ++i) {
                gld_lds16(srcs[i], &lds[cur ^ 1][ldsoff + i * 1024]);
                srcs[i] += 512;
            }
            asm volatile("s_waitcnt vmcnt(8)" ::: "memory");
        } else {
            asm volatile("s_waitcnt vmcnt(0)" ::: "memory");
        }
        __builtin_amdgcn_s_barrier();

        const char* L = lds[cur];
        short8 ah[8], al[8];
        #pragma unroll
        for (int m = 0; m < 8; ++m) {
            ah[m] = *reinterpret_cast<const short8*>(L +         (wr * 8 + m) * 1024 + lane * 16);
            al[m] = *reinterpret_cast<const short8*>(L + 16384 + (wr * 8 + m) * 1024 + lane * 16);
        }
        __builtin_amdgcn_s_setprio(1);
        #pragma unroll
        for (int n = 0; n < 4; ++n) {
            short8 bh = *reinterpret_cast<const short8*>(L + 32768 + (wc * 4 + n) * 1024 + lane * 16);
            short8 bl = *reinterpret_cast<const short8*>(L + 49152 + (wc * 4 + n) * 1024 + lane * 16);
            #pragma unroll
            for (int m = 0; m < 8; ++m) {
                acc[m][n] = __builtin_amdgcn_mfma_f32_16x16x32_bf16(ah[m], bh, acc[m][n], 0, 0, 0);
                acc[m][n] = __builtin_amdgcn_mfma_f32_16x16x32_bf16(ah[m], bl, acc[m][n], 0, 0, 0);
                acc[m][n] = __builtin_amdgcn_mfma_f32_16x16x32_bf16(al[m], bh, acc[m][n], 0, 0, 0);
            }
        }
        __builtin_amdgcn_s_setprio(0);
        asm volatile("" ::: "memory");
        __builtin_amdgcn_s_barrier();
        asm volatile("" ::: "memory");
        cur ^= 1;
    }

    const int row0 = blockIdx.y * 256 + wr * 128;
    const int col0 = blockIdx.x * 256 + wc * 64;
    float* Cb = C + (long)b * cBatch;
    #pragma unroll
    for (int m = 0; m < 8; ++m)
        #pragma unroll
        for (int n = 0; n < 4; ++n) {
            const int col = col0 + n * 16 + (lane & 15);
            #pragma unroll
            for (int j = 0; j < 4; ++j) {
                const int row = row0 + m * 16 + (lane >> 4) * 4 + j;
                float v = acc[m][n][j];
                if (BIAS) v += bias[row];
                Cb[(long)row * N + col] = v;
            }
        }
}

__global__ __launch_bounds__(256) void zero_buf(float* p, int n) {
    for (int i = blockIdx.x * 256 + threadIdx.x; i < n; i += gridDim.x * 256) p[i] = 0.f;
}

// ---------------------------------------------------------------------------
// gemm_w3: 128x128 split-bf16 MFMA GEMM computing W3 = Amat @ Wq, emitting
// A-operand hi/lo frags DIRECTLY (LDS bounce).  grid (4, 4, NB), 256 thr.
// ---------------------------------------------------------------------------
__global__ __launch_bounds__(256) void gemm_w3(
    const unsigned short* __restrict__ Ah, const unsigned short* __restrict__ Al,
    const unsigned short* __restrict__ Bh, const unsigned short* __restrict__ Bl,
    unsigned short* __restrict__ w3h, unsigned short* __restrict__ w3l)
{
    const int b    = blockIdx.z;
    const int tid  = threadIdx.x;
    const int lane = tid & 63;
    const int wid  = tid >> 6;
    const int wr   = wid >> 1;
    const int wc   = wid & 1;

    __shared__ __align__(16) char lds[64 * 132 * 4];   // staging uses first 32KB

    f32x4 acc[4][4];
    #pragma unroll
    for (int m = 0; m < 4; ++m)
        #pragma unroll
        for (int n = 0; n < 4; ++n) acc[m][n] = (f32x4){0.f, 0.f, 0.f, 0.f};

    const int rb0 = b * 32 + blockIdx.y * 8;
    const int cb0 = blockIdx.x * 8;

    const unsigned short* srcs[8];
    #pragma unroll
    for (int i = 0; i < 8; ++i) {
        const int blk = wid * 8 + i;
        const int sub = blk & 7;
        const unsigned short* s;
        if (blk < 8)       s = Ah + ((long)(rb0 + sub) * 16 << 9);
        else if (blk < 16) s = Al + ((long)(rb0 + sub) * 16 << 9);
        else if (blk < 24) s = Bh + ((long)(cb0 + sub) * 16 << 9);
        else               s = Bl + ((long)(cb0 + sub) * 16 << 9);
        srcs[i] = s + lane * 8;
    }

    for (int kt = 0; kt < 16; ++kt) {
        #pragma unroll
        for (int i = 0; i < 8; ++i) {
            gld_lds16(srcs[i], lds + (wid * 8 + i) * 1024);
            srcs[i] += 512;
        }
        __syncthreads();

        short8 ah[4], al[4], bh[4], bl[4];
        #pragma unroll
        for (int m = 0; m < 4; ++m) {
            ah[m] = *reinterpret_cast<const short8*>(lds +         (wr * 4 + m) * 1024 + lane * 16);
            al[m] = *reinterpret_cast<const short8*>(lds +  8192 + (wr * 4 + m) * 1024 + lane * 16);
        }
        #pragma unroll
        for (int n = 0; n < 4; ++n) {
            bh[n] = *reinterpret_cast<const short8*>(lds + 16384 + (wc * 4 + n) * 1024 + lane * 16);
            bl[n] = *reinterpret_cast<const short8*>(lds + 24576 + (wc * 4 + n) * 1024 + lane * 16);
        }
        #pragma unroll
        for (int m = 0; m < 4; ++m)
            #pragma unroll
            for (int n = 0; n < 4; ++n) {
                acc[m][n] = __builtin_amdgcn_mfma_f32_16x16x32_bf16(ah[m], bh[n], acc[m][n], 0, 0, 0);
                acc[m][n] = __builtin_amdgcn_mfma_f32_16x16x32_bf16(ah[m], bl[n], acc[m][n], 0, 0, 0);
                acc[m][n] = __builtin_amdgcn_mfma_f32_16x16x32_bf16(al[m], bh[n], acc[m][n], 0, 0, 0);
            }
        __syncthreads();
    }

    // epilogue: bounce C in 64-row halves -> emit frags
    float* Ct = (float*)lds;   // [64][132]
    #pragma unroll
    for (int hf = 0; hf < 2; ++hf) {
        __syncthreads();
        if (wr == hf) {
            #pragma unroll
            for (int m = 0; m < 4; ++m)
                #pragma unroll
                for (int n = 0; n < 4; ++n)
                    #pragma unroll
                    for (int j = 0; j < 4; ++j)
                        Ct[(m * 16 + (lane >> 4) * 4 + j) * 132 + wc * 64 + n * 16 + (lane & 15)]
                            = acc[m][n][j];
        }
        __syncthreads();
        #pragma unroll
        for (int i = 0; i < 4; ++i) {
            const int blkid = wid * 4 + i;       // 0..15
            const int rbl = blkid >> 2, ktl = blkid & 3;
            short8 hv, lv;
            #pragma unroll
            for (int jj = 0; jj < 8; ++jj) {
                float v = Ct[(rbl * 16 + (lane & 15)) * 132 + ktl * 32 + (lane >> 4) * 8 + jj];
                unsigned short hh = f2bf(v);
                hv[jj] = (short)hh;
                lv[jj] = (short)f2bf(v - bf2f(hh));
            }
            const int rbG = b * 32 + blockIdx.y * 8 + hf * 4 + rbl;
            const int ktG = blockIdx.x * 4 + ktl;
            const long base = ((long)rbG * 16 + ktG) * 512 + lane * 8;
            *reinterpret_cast<short8*>(w3h + base) = hv;
            *reinterpret_cast<short8*>(w3l + base) = lv;
        }
    }
}

// ---------------------------------------------------------------------------
// ctx_fold2: Amat tile folded with normalized ctx, emitted directly as
// A-operand hi/lo frags.  grid (8 o-slices, NHEAD, NB), 256 thr.
// ---------------------------------------------------------------------------
__global__ __launch_bounds__(256) void ctx_fold2(
    const float* __restrict__ w_out, const float* __restrict__ ctx,
    const float* __restrict__ ssum,
    unsigned short* __restrict__ amh, unsigned short* __restrict__ aml)
{
    const int o0 = blockIdx.x * 64;
    const int h  = blockIdx.y;
    const int b  = blockIdx.z;
    const int tid = threadIdx.x;

    __shared__ float Wo[64][65];
    __shared__ float Ct[64][65];
    __shared__ float At[64][65];

    for (int idx = tid; idx < 64 * 16; idx += 256) {
        const int r = idx >> 4;
        const int c = (idx & 15) * 4;
        float4 w4 = *reinterpret_cast<const float4*>(&w_out[(long)(o0 + r) * CDIM + h * 64 + c]);
        Wo[r][c + 0] = w4.x; Wo[r][c + 1] = w4.y; Wo[r][c + 2] = w4.z; Wo[r][c + 3] = w4.w;
        float4 c4 = *reinterpret_cast<const float4*>(&ctx[(((long)(b * NHEAD + h) * 64 + r) * 64) + c]);
        Ct[r][c + 0] = c4.x; Ct[r][c + 1] = c4.y; Ct[r][c + 2] = c4.z; Ct[r][c + 3] = c4.w;
    }
    __syncthreads();

    const int to = tid >> 4, td = tid & 15;
    float acc[4][4];
    #pragma unroll
    for (int i = 0; i < 4; ++i)
        #pragma unroll
        for (int j = 0; j < 4; ++j) acc[i][j] = 0.f;

    for (int e = 0; e < 64; ++e) {
        float ro[4], rd[4];
        #pragma unroll
        for (int i = 0; i < 4; ++i) ro[i] = Wo[to * 4 + i][e];
        #pragma unroll
        for (int j = 0; j < 4; ++j) rd[j] = Ct[td * 4 + j][e];
        #pragma unroll
        for (int i = 0; i < 4; ++i)
            #pragma unroll
            for (int j = 0; j < 4; ++j) acc[i][j] += ro[i] * rd[j];
    }

    #pragma unroll
    for (int j = 0; j < 4; ++j) {
        const float s = 1.f / ssum[b * 512 + h * 64 + td * 4 + j];
        #pragma unroll
        for (int i = 0; i < 4; ++i)
            At[to * 4 + i][td * 4 + j] = acc[i][j] * s;
    }
    __syncthreads();

    const int g = tid >> 6, lane = tid & 63;
    #pragma unroll
    for (int kt_l = 0; kt_l < 2; ++kt_l) {
        short8 hv, lv;
        #pragma unroll
        for (int jj = 0; jj < 8; ++jj) {
            float v = At[g * 16 + (lane & 15)][kt_l * 32 + (lane >> 4) * 8 + jj];
            unsigned short hh = f2bf(v);
            hv[jj] = (short)hh;
            lv[jj] = (short)f2bf(v - bf2f(hh));
        }
        const long base = (((long)(b * 32 + (o0 >> 4) + g) * 16) + (h * 2 + kt_l)) * 512 + lane * 8;
        *reinterpret_cast<short8*>(amh + base) = hv;
        *reinterpret_cast<short8*>(aml + base) = lv;
    }
}

// ---------------------------------------------------------------------------
extern "C" void kernel_launch(void* const* d_in, const int* in_sizes, int n_in,
                              void* d_out, int out_size, void* d_ws, size_t ws_size,
                              hipStream_t stream) {
    (void)in_sizes; (void)n_in; (void)out_size; (void)ws_size;
    const float* x     = (const float*)d_in[0];
    const float* w_qkv = (const float*)d_in[1];
    const float* w_out = (const float*)d_in[2];
    const float* b_out = (const float*)d_in[3];
    float* out = (float*)d_out;

    char* ws = (char*)d_ws;
    unsigned short* xh   = (unsigned short*)(ws + 134217728L);        // 32 MiB
    unsigned short* xl   = (unsigned short*)(ws + 167772160L);        // 32 MiB
    unsigned short* wkvh = (unsigned short*)(ws + 201326592L);        // 1 MiB
    unsigned short* wkvl = (unsigned short*)(ws + 202375168L);        // 1 MiB
    float*          ssum = (float*)(ws + 203423744L);                 // 16 KiB
    float*          ctx  = (float*)(ws + 203440128L);                 // 1 MiB
    unsigned short* amh  = (unsigned short*)(ws + 16777216L);         // 4 MiB
    unsigned short* aml  = (unsigned short*)(ws + 20971520L);         // 4 MiB
    unsigned short* wqh  = (unsigned short*)(ws + 25165824L);         // 1 MiB
    unsigned short* wql  = (unsigned short*)(ws + 26214400L);         // 1 MiB
    unsigned short* w3h  = (unsigned short*)(ws + 27262976L);         // 4 MiB
    unsigned short* w3l  = (unsigned short*)(ws + 31457280L);         // 4 MiB

    // 1) conversions + zero accumulators
    convert_x<<<dim3(64, 16, NB), 256, 0, stream>>>(x, xh, xl);
    convert_w<<<dim3(64, 16), 64, 0, stream>>>(w_qkv + 512L * CDIM, wkvh, wkvl);
    zero_buf<<<256, 256, 0, stream>>>(ssum, (16384 + 1048576) / 4);

    // 2) FUSED (4-wave proven): KV GEMM + exp + row sums + ctx accumulation
    fused_kv_ctx<<<dim3(16, NHEAD, NB), 256, 0, stream>>>(
        wkvh, wkvl, xh, xl, ctx, ssum);

    // 3) Wq -> B-frags
    convert_b<<<dim3(32, 16), 64, 0, stream>>>(w_qkv, CDIM, wqh, wql);

    // 4) fold ctx into W_out -> Amat frags directly
    ctx_fold2<<<dim3(8, NHEAD, NB), 256, 0, stream>>>(w_out, ctx, ssum, amh, aml);

    // 5) W3 = Amat @ Wq via MFMA, emitting W3 frags directly
    gemm_w3<<<dim3(4, 4, NB), 256, 0, stream>>>(amh, aml, wqh, wql, w3h, w3l);

    // 6) out = W3 @ x + b_out  (2-phase 256^2, proven)
    gemm_mfma256<16, true><<<dim3(16, 2, NB), 512, 0, stream>>>(
        w3h, w3l, xh, xl, out, b_out, NSP, 32, 256, (long)CDIM * NSP);
}